// Round 10
// baseline (139.813 us; speedup 1.0000x reference)
//
#include <hip/hip_runtime.h>

// SAGEConv: h[50000,64] f32, src/dst[800000] int32, W[128,64] f32, b[64] f32
// out = concat(h, mean_{in-edges}(h[src])) @ W + b
//
// R10: 3 GPU ops (memset 3KB, prep, fused). vs R9, gather restructured:
//  - 8 lanes/edge x dwordx4 (16B): 1KB per wave-load = 8 edge rows ->
//    gather load instructions halve (200k -> 100k wave-loads).
//  - node-pair software pipelining: 2 nodes' loads (4 wave-loads, 32 edges)
//    in flight before the first wait -> per-node latency stalls halve.
//  - bf16->f32 via shift/mask on packed uints (no cvt chain).
// prep / in-LDS CSR build / MLP unchanged from R9.
// Lessons kept: read-side shfl reduction (R6: feature-wise LDS atomics =
// 51M ds-RMW = disaster); rank-capture single-atomic-pass CSR (R9).

#define IN_FEAT 64
#define KB_SHIFT 6            // 64 nodes per bucket
#define BKN 64
#define CAP 2048              // pairs per bucket (mean 1024 at E=800k,K=782)
#define KMAX 1024             // supports n_nodes <= 65536

__device__ __forceinline__ unsigned short f2bf(float f) {
    unsigned u = __float_as_uint(f);
    return (unsigned short)((u + 0x7FFFu + ((u >> 16) & 1u)) >> 16);
}
__device__ __forceinline__ float bf2f(unsigned short s) {
    return __uint_as_float(((unsigned)s) << 16);
}
// accumulate 8 packed bf16 (uint4) into 8 f32 accumulators
__device__ __forceinline__ void acc8(float* a, uint4 u) {
    a[0] += __uint_as_float(u.x << 16);
    a[1] += __uint_as_float(u.x & 0xFFFF0000u);
    a[2] += __uint_as_float(u.y << 16);
    a[3] += __uint_as_float(u.y & 0xFFFF0000u);
    a[4] += __uint_as_float(u.z << 16);
    a[5] += __uint_as_float(u.z & 0xFFFF0000u);
    a[6] += __uint_as_float(u.w << 16);
    a[7] += __uint_as_float(u.w & 0xFFFF0000u);
}

// ---- k1: blocks [0,conv_tiles): h->bf16 ; rest: bucket the edges -----------
__global__ __launch_bounds__(512) void sage_prep(
    const float* __restrict__ h, const int* __restrict__ src,
    const int* __restrict__ dst,
    unsigned short* __restrict__ hb, unsigned* __restrict__ pairs,
    int* __restrict__ cursorG,
    int n4, int n_edges, int conv_tiles, int K)
{
    __shared__ int cnt[KMAX];
    __shared__ int base[KMAX];
    int t = (int)threadIdx.x;

    if ((int)blockIdx.x < conv_tiles) {
        int tb = blockIdx.x * 8192;
        #pragma unroll
        for (int i = 0; i < 16; ++i) {
            int idx = tb + t + i * 512;            // float4 index
            if (idx < n4) {
                float4 v = ((const float4*)h)[idx];
                ushort4 r;
                r.x = f2bf(v.x); r.y = f2bf(v.y);
                r.z = f2bf(v.z); r.w = f2bf(v.w);
                ((ushort4*)hb)[idx] = r;
            }
        }
    } else {
        for (int k = t; k < K; k += 512) cnt[k] = 0;
        __syncthreads();
        int tb = ((int)blockIdx.x - conv_tiles) * 8192;
        int kb[16]; unsigned pk[16]; int rk[16];
        #pragma unroll 4
        for (int i = 0; i < 16; ++i) {
            int e = tb + t + i * 512;
            kb[i] = -1;
            if (e < n_edges) {
                int d = dst[e], s = src[e];
                int k = d >> KB_SHIFT;
                kb[i] = k;
                pk[i] = ((unsigned)s << KB_SHIFT) | (unsigned)(d & (BKN - 1));
                rk[i] = atomicAdd(&cnt[k], 1);     // rank within (tile,bucket)
            }
        }
        __syncthreads();
        for (int k = t; k < K; k += 512) {
            int c = cnt[k];
            base[k] = c ? atomicAdd(&cursorG[k], c) : 0;
        }
        __syncthreads();
        #pragma unroll 4
        for (int i = 0; i < 16; ++i) {
            if (kb[i] >= 0) {
                int pos = base[kb[i]] + rk[i];
                if (pos < CAP)                      // safety clamp
                    pairs[((size_t)kb[i] << 11) + pos] = pk[i];
            }
        }
    }
}

// ---- k2: per-bucket local CSR + gather-mean + MLP --------------------------
// One block (512 thr, 8 waves) per 64-node bucket.
//  A: CSR in LDS, rank captured from the count atomic (single atomic pass).
//  B: wave w gathers nodes w*8..w*8+7 in PAIRS: 8 lanes/edge x uint4 (16B),
//     2-deep unroll per node, 2 nodes in flight (4 wave-loads / 32 edges),
//     3-step __shfl_xor(8,16,32) reduce, mean -> bf16 hn (row pad 80 shorts:
//     160B, 16B-aligned, start-bank cycles 0/8/16/24).
//  C: MLP: wave w, pass p: node w*8+p*4+sub4, cols 4q..4q+3; self row f32
//     global (broadcast), W rows ds_read_b128 shared by 4 nodes.
__global__ __launch_bounds__(512, 6) void sage_fused(
    const unsigned short* __restrict__ hb,
    const float* __restrict__ h,
    const unsigned* __restrict__ pairs,
    const int* __restrict__ cursorG,
    const float* __restrict__ W,     // [128,64] row-major
    const float* __restrict__ bias,
    float* __restrict__ out,
    int n_nodes)
{
    __shared__ float Wsh[128][64];        // 32 KB
    __shared__ float bsh[64];
    __shared__ unsigned short hn[BKN][80];// 10.25 KB (bf16 means, 160B rows)
    __shared__ int   list[CAP];           // 8 KB
    __shared__ int   cnt[BKN];
    __shared__ int   rs[BKN + 1];
    // total ~50.5 KB -> 3 blocks/CU (24 waves)

    const int t = (int)threadIdx.x;
    {   // stage W: 2048 float4s, 4 per thread
        float4* wd = (float4*)&Wsh[0][0];
        const float4* wsv = (const float4*)W;
        wd[t]        = wsv[t];
        wd[t + 512]  = wsv[t + 512];
        wd[t + 1024] = wsv[t + 1024];
        wd[t + 1536] = wsv[t + 1536];
    }
    if (t < 64) { bsh[t] = bias[t]; cnt[t] = 0; }
    __syncthreads();

    const int b   = (int)blockIdx.x;
    const int nlo = b << KB_SHIFT;
    int m = cursorG[b]; if (m > CAP) m = CAP;
    const unsigned* pb = pairs + ((size_t)b << 11);

    // A: single-atomic-pass local CSR
    unsigned lp[4]; int lr[4];
    #pragma unroll
    for (int i = 0; i < 4; ++i) {
        int idx = t + i * 512;
        lr[i] = -1;
        if (idx < m) {
            lp[i] = pb[idx];
            lr[i] = atomicAdd(&cnt[lp[i] & (BKN - 1)], 1);
        }
    }
    __syncthreads();
    if (t < 64) {            // wave 0 scans the 64 counters
        int v = cnt[t];
        int incl = v;
        #pragma unroll
        for (int off = 1; off < 64; off <<= 1) {
            int x = __shfl_up(incl, off);
            if (t >= off) incl += x;
        }
        rs[t] = incl - v;
        if (t == 63) rs[64] = incl;
    }
    __syncthreads();
    #pragma unroll
    for (int i = 0; i < 4; ++i)
        if (lr[i] >= 0)
            list[rs[lp[i] & (BKN - 1)] + lr[i]] = (int)(lp[i] >> KB_SHIFT);
    __syncthreads();

    const int w    = t >> 6;
    const int lane = t & 63;
    const int sub  = lane >> 3;      // gather: edge subgroup 0..7
    const int q8   = lane & 7;       // 16B group within the 128B row

    // B: gather — wave w owns nodes w*8..w*8+7, processed in pairs
    for (int i = 0; i < 8; i += 2) {
        int nlA = w * 8 + i, nlB = nlA + 1;
        int nA  = nlo + nlA;
        if (nA >= n_nodes) break;              // wave-uniform
        bool hasB = (nlo + nlB) < n_nodes;
        int begA = rs[nlA], endA = rs[nlA + 1];
        int begB = hasB ? rs[nlB] : 0, endB = hasB ? rs[nlB + 1] : 0;

        float aA[8] = {0,0,0,0,0,0,0,0};
        float aB[8] = {0,0,0,0,0,0,0,0};
        int eA = begA + sub, eB = begB + sub;

        // co-iterated main loop: 4 wave-loads (32 edges) in flight
        while ((eA + 8 < endA) & (eB + 8 < endB)) {
            int sA0 = list[eA], sA1 = list[eA + 8];
            int sB0 = list[eB], sB1 = list[eB + 8];
            uint4 uA0 = *(const uint4*)(hb + ((size_t)sA0 << 6) + q8 * 8);
            uint4 uA1 = *(const uint4*)(hb + ((size_t)sA1 << 6) + q8 * 8);
            uint4 uB0 = *(const uint4*)(hb + ((size_t)sB0 << 6) + q8 * 8);
            uint4 uB1 = *(const uint4*)(hb + ((size_t)sB1 << 6) + q8 * 8);
            acc8(aA, uA0); acc8(aA, uA1);
            acc8(aB, uB0); acc8(aB, uB1);
            eA += 16; eB += 16;
        }
        while (eA + 8 < endA) {
            int s0 = list[eA], s1 = list[eA + 8];
            uint4 u0 = *(const uint4*)(hb + ((size_t)s0 << 6) + q8 * 8);
            uint4 u1 = *(const uint4*)(hb + ((size_t)s1 << 6) + q8 * 8);
            acc8(aA, u0); acc8(aA, u1);
            eA += 16;
        }
        while (eB + 8 < endB) {
            int s0 = list[eB], s1 = list[eB + 8];
            uint4 u0 = *(const uint4*)(hb + ((size_t)s0 << 6) + q8 * 8);
            uint4 u1 = *(const uint4*)(hb + ((size_t)s1 << 6) + q8 * 8);
            acc8(aB, u0); acc8(aB, u1);
            eB += 16;
        }
        if (eA < endA) {
            int s0 = list[eA];
            uint4 u0 = *(const uint4*)(hb + ((size_t)s0 << 6) + q8 * 8);
            acc8(aA, u0);
        }
        if (eB < endB) {
            int s0 = list[eB];
            uint4 u0 = *(const uint4*)(hb + ((size_t)s0 << 6) + q8 * 8);
            acc8(aB, u0);
        }

        // reduce across the 8 edge-subgroups (masks 8,16,32)
        #pragma unroll
        for (int mm = 8; mm < 64; mm <<= 1) {
            #pragma unroll
            for (int c = 0; c < 8; ++c) {
                aA[c] += __shfl_xor(aA[c], mm);
                aB[c] += __shfl_xor(aB[c], mm);
            }
        }
        int degA = endA - begA;
        float invA = (degA > 0) ? (1.0f / (float)degA) : 0.f;
        int degB = endB - begB;
        float invB = (degB > 0) ? (1.0f / (float)degB) : 0.f;
        if (sub == 0) {
            uint4 r;
            r.x = ((unsigned)f2bf(aA[1] * invA) << 16) | f2bf(aA[0] * invA);
            r.y = ((unsigned)f2bf(aA[3] * invA) << 16) | f2bf(aA[2] * invA);
            r.z = ((unsigned)f2bf(aA[5] * invA) << 16) | f2bf(aA[4] * invA);
            r.w = ((unsigned)f2bf(aA[7] * invA) << 16) | f2bf(aA[6] * invA);
            *(uint4*)&hn[nlA][q8 * 8] = r;
            if (hasB) {
                uint4 rb;
                rb.x = ((unsigned)f2bf(aB[1] * invB) << 16) | f2bf(aB[0] * invB);
                rb.y = ((unsigned)f2bf(aB[3] * invB) << 16) | f2bf(aB[2] * invB);
                rb.z = ((unsigned)f2bf(aB[5] * invB) << 16) | f2bf(aB[4] * invB);
                rb.w = ((unsigned)f2bf(aB[7] * invB) << 16) | f2bf(aB[6] * invB);
                *(uint4*)&hn[nlB][q8 * 8] = rb;
            }
        }
    }
    __builtin_amdgcn_wave_barrier();   // hn is wave-private; scheduling fence

    // C: MLP — wave w, pass p: node w*8 + p*4 + sub4
    const int sub4 = lane >> 4;
    const int q    = lane & 15;
    #pragma unroll
    for (int p = 0; p < 2; ++p) {
        int nl = w * 8 + p * 4 + sub4;
        int n  = nlo + nl;
        if (n < n_nodes) {
            const float* hrow = h + ((size_t)n << 6);
            float4 o = ((const float4*)bsh)[q];
            #pragma unroll
            for (int k4 = 0; k4 < 16; ++k4) {
                const float4 hq = *(const float4*)(hrow + k4 * 4);   // bcast x16
                #pragma unroll
                for (int c = 0; c < 4; ++c) {
                    float hv = (&hq.x)[c];
                    const float4 wv = *(const float4*)&Wsh[k4 * 4 + c][q * 4];
                    o.x = fmaf(hv, wv.x, o.x);
                    o.y = fmaf(hv, wv.y, o.y);
                    o.z = fmaf(hv, wv.z, o.z);
                    o.w = fmaf(hv, wv.w, o.w);
                }
            }
            #pragma unroll 16
            for (int k = 0; k < 64; ++k) {
                float hv = bf2f(hn[nl][k]);
                const float4 wv = *(const float4*)&Wsh[64 + k][q * 4];
                o.x = fmaf(hv, wv.x, o.x);
                o.y = fmaf(hv, wv.y, o.y);
                o.z = fmaf(hv, wv.z, o.z);
                o.w = fmaf(hv, wv.w, o.w);
            }
            *(float4*)(out + ((size_t)n << 6) + q * 4) = o;
        }
    }
}

extern "C" void kernel_launch(void* const* d_in, const int* in_sizes, int n_in,
                              void* d_out, int out_size, void* d_ws, size_t ws_size,
                              hipStream_t stream) {
    const float* h   = (const float*)d_in[0];
    const int*   src = (const int*)d_in[1];
    const int*   dst = (const int*)d_in[2];
    const float* W   = (const float*)d_in[3];
    const float* b   = (const float*)d_in[4];
    float* out = (float*)d_out;

    const int n_nodes = in_sizes[0] / IN_FEAT;
    const int n_edges = in_sizes[1];
    const int K  = (n_nodes + BKN - 1) >> KB_SHIFT;    // 782
    const int n4 = n_nodes * (IN_FEAT / 4);            // 800000 float4s

    // ws: hb[N*64 ushort] | pairs[K*CAP u32] | cursorG[K]
    unsigned short* hb = (unsigned short*)d_ws;
    unsigned* pairs    = (unsigned*)(hb + (size_t)n_nodes * IN_FEAT);
    int* cursorG       = (int*)(pairs + (size_t)K * CAP);

    hipMemsetAsync(cursorG, 0, (size_t)K * sizeof(int), stream);

    const int conv_tiles   = (n4 + 8191) / 8192;       // 98
    const int bucket_tiles = (n_edges + 8191) / 8192;  // 98
    sage_prep<<<conv_tiles + bucket_tiles, 512, 0, stream>>>(
        h, src, dst, hb, pairs, cursorG, n4, n_edges, conv_tiles, K);
    sage_fused<<<K, 512, 0, stream>>>(hb, h, pairs, cursorG, W, b, out, n_nodes);
}